// Round 11
// baseline (20.657 us; speedup 1.0000x reference)
//
#include <hip/hip_runtime.h>
#include <math.h>

#define TPB 256
#define RPB 18                   // rotations per block
#define NBLK 2048                // 2048 * 18 = 36864
#define LOG2E2 2.0813689810056077f   // (log2 e)^2
#define CLAMP_S 2.0813689810e-8f     // 1e-8 * LOG2E2
#define LN_LOG2E 0.3665129205816643  // ln(log2 e), double

#if __has_builtin(__builtin_amdgcn_rsqf)
#define FAST_RSQ(x) __builtin_amdgcn_rsqf(x)
#else
#define FAST_RSQ(x) rsqrtf(x)
#endif
#if __has_builtin(__builtin_amdgcn_exp2f)
#define FAST_EXP2(x) __builtin_amdgcn_exp2f(x)
#else
#define FAST_EXP2(x) exp2f(x)
#endif

// {-Z0,-Z4,-Z8,-Z1,-Z2,-Z5, trZ} for FMA-friendly x = trZ - tr(Z R)
__device__ __forceinline__ void compute_Z_neg(const float* __restrict__ L, float zo[7]) {
    float a = L[0], l10 = L[3], c = L[4], d = L[6], e = L[7], f = L[8];
    float ia = 1.0f / a, ic = 1.0f / c, iff = 1.0f / f;
    float m00 = ia;
    float m10 = -l10 * ia * ic;
    float m11 = ic;
    float m20 = (l10 * e - c * d) * ia * ic * iff;
    float m21 = -e * ic * iff;
    float m22 = iff;
    float Z0 = m00*m00 + m10*m10 + m20*m20;
    float Z1 = m10*m11 + m20*m21;
    float Z2 = m20*m22;
    float Z4 = m11*m11 + m21*m21;
    float Z5 = m21*m22;
    float Z8 = m22*m22;
    zo[0] = -Z0; zo[1] = -Z4; zo[2] = -Z8;
    zo[3] = -Z1; zo[4] = -Z2; zo[5] = -Z5;
    zo[6] = Z0 + Z4 + Z8;
}

__device__ __forceinline__ void quat_to_mat(const float q[4], float R[9]) {
    float n = sqrtf(q[0]*q[0] + q[1]*q[1] + q[2]*q[2] + q[3]*q[3]);
    float w = q[0]/n, x = q[1]/n, y = q[2]/n, z = q[3]/n;
    R[0] = 1.f - 2.f*(y*y + z*z);
    R[1] = 2.f*(x*y - w*z);
    R[2] = 2.f*(x*z + w*y);
    R[3] = 2.f*(x*y + w*z);
    R[4] = 1.f - 2.f*(x*x + z*z);
    R[5] = 2.f*(y*z - w*x);
    R[6] = 2.f*(x*z - w*y);
    R[7] = 2.f*(y*z + w*x);
    R[8] = 1.f - 2.f*(x*x + y*y);
}

// K1: one thread <-> one b; block <-> rotation tile. Rotation address is
// wave-uniform (scalar/broadcast loads); no LDS, no barriers, no reduction.
// part values carry a 1/LOG2E factor ((log2e)^2-prescaled Z), fixed in k_fin.
__global__ __launch_bounds__(TPB) void k_part(
    const float* __restrict__ cov_tril,
    const float* __restrict__ grids,
    float* __restrict__ part)
{
    const int b = threadIdx.x;

    float zo[7];
    compute_Z_neg(cov_tril + b * 9, zo);
    const float f0  = zo[0] * LOG2E2;   // -Z00
    const float f4  = zo[1] * LOG2E2;   // -Z11
    const float f8  = zo[2] * LOG2E2;   // -Z22
    const float f13 = zo[3] * LOG2E2;   // -Z01 (slots 1,3)
    const float f26 = zo[4] * LOG2E2;   // -Z02 (slots 2,6)
    const float f57 = zo[5] * LOG2E2;   // -Z12 (slots 5,7)
    const float trZ = zo[6] * LOG2E2;

    const float* __restrict__ G = grids + (size_t)blockIdx.x * RPB * 9;

    float acc = 0.f;
#pragma unroll
    for (int r = 0; r < RPB; ++r) {
        const float* g = G + r * 9;     // wave-uniform address
        float x = trZ;
        x = fmaf(f0,  g[0], x);
        x = fmaf(f13, g[1], x);
        x = fmaf(f26, g[2], x);
        x = fmaf(f13, g[3], x);
        x = fmaf(f4,  g[4], x);
        x = fmaf(f57, g[5], x);
        x = fmaf(f26, g[6], x);
        x = fmaf(f57, g[7], x);
        x = fmaf(f8,  g[8], x);
        x = fmaxf(x, CLAMP_S);
        float rr = FAST_RSQ(x);          // = (1/p)/LOG2E
        float e  = FAST_EXP2(-(x * rr)); // = exp2(-LOG2E*p) = exp(-p)
        acc = fmaf(e, rr, acc);          // += exp(-p)/(LOG2E*p)
    }

    part[(size_t)blockIdx.x * TPB + b] = acc;   // coalesced
}

// K2: 256 blocks (one per b) x 1 wave. Fixed-order fp64 segment sums +
// deterministic shuffle tree; lane 0 does the quaternion part.
__global__ __launch_bounds__(64) void k_fin(
    const float* __restrict__ gt_quat,
    const float* __restrict__ mode_quat,
    const float* __restrict__ cov_tril,
    const float* __restrict__ part,
    float* __restrict__ out, int n_total)
{
    const int b    = blockIdx.x;
    const int lane = threadIdx.x;

    double s = 0.0;
    const int seg = NBLK / 64;          // 32 partials per lane, fixed order
#pragma unroll 8
    for (int j = 0; j < seg; ++j)
        s += (double)part[(size_t)(lane * seg + j) * TPB + b];

#pragma unroll
    for (int off = 32; off > 0; off >>= 1)
        s += __shfl_down(s, off, 64);

    if (lane == 0) {
        float zo[7];
        compute_Z_neg(cov_tril + b * 9, zo);

        float q0[4] = {mode_quat[b*4+0], mode_quat[b*4+1], mode_quat[b*4+2], mode_quat[b*4+3]};
        float qg[4] = {gt_quat[b*4+0],   gt_quat[b*4+1],   gt_quat[b*4+2],   gt_quat[b*4+3]};
        float R0[9], Rg[9];
        quat_to_mat(q0, R0);
        quat_to_mat(qg, Rg);

        float Rr[9];
#pragma unroll
        for (int i = 0; i < 3; ++i)
#pragma unroll
            for (int j = 0; j < 3; ++j)
                Rr[i*3+j] = R0[0*3+i]*Rg[0*3+j] + R0[1*3+i]*Rg[1*3+j] + R0[2*3+i]*Rg[2*3+j];

        float x = zo[6];
        x = fmaf(zo[0], Rr[0], x);
        x = fmaf(zo[1], Rr[4], x);
        x = fmaf(zo[2], Rr[8], x);
        x = fmaf(zo[3], Rr[1] + Rr[3], x);
        x = fmaf(zo[4], Rr[2] + Rr[6], x);
        x = fmaf(zo[5], Rr[5] + Rr[7], x);

        float power = sqrtf(fmaxf(x, 1e-8f));
        // s carries 1/LOG2E: log(s*LOG2E) = log(s) + ln(log2 e)
        float logF  = (float)(log(s) + LN_LOG2E - log((double)n_total));
        out[b] = logF + power + logf(power);
    }
}

extern "C" void kernel_launch(void* const* d_in, const int* in_sizes, int n_in,
                              void* d_out, int out_size, void* d_ws, size_t ws_size,
                              hipStream_t stream) {
    const float* gt    = (const float*)d_in[0];
    const float* mode  = (const float*)d_in[1];
    const float* cov   = (const float*)d_in[2];
    const float* grids = (const float*)d_in[3];
    float* out = (float*)d_out;

    int n_total = in_sizes[3] / 9;     // 36864

    float* part = (float*)d_ws;        // 2048*256 floats = 2 MB (ws ~256 MB per fill evidence)

    k_part<<<NBLK, TPB, 0, stream>>>(cov, grids, part);
    k_fin<<<256, 64, 0, stream>>>(gt, mode, cov, part, out, n_total);
}

// Round 12
// 16.403 us; speedup vs baseline: 1.2593x; 1.2593x over previous
//
#include <hip/hip_runtime.h>
#include <math.h>

#define TPB 256
#define BPB 8                    // batch elements per block
#define CHUNK 256                // rotations staged into LDS per pass
#define NCHUNKS 3                // chunks per block-tile
#define NCHUNK (CHUNK * NCHUNKS) // 768 rotations per block-tile
#define NTILES 48                // 48 * 768 = 36864
#define BGRPS 32                 // 256 / BPB
#define LOG2E 1.44269504088896340736f

#if __has_builtin(__builtin_amdgcn_rsqf)
#define FAST_RSQ(x) __builtin_amdgcn_rsqf(x)
#else
#define FAST_RSQ(x) rsqrtf(x)
#endif
#if __has_builtin(__builtin_amdgcn_exp2f)
#define FAST_EXP2(x) __builtin_amdgcn_exp2f(x)
#else
#define FAST_EXP2(x) exp2f(x)
#endif

// async global->LDS, 16B per lane (wave: 64 lanes x 16B = 1024B per call).
// LDS dest = wave-uniform base + lane*16 (linear); global src is per-lane.
__device__ __forceinline__ void async_copy16(void* lds, const void* g) {
    __builtin_amdgcn_global_load_lds(
        (const __attribute__((address_space(1))) unsigned int*)g,
        (__attribute__((address_space(3))) unsigned int*)lds, 16, 0, 0);
}

// {-Z0,-Z4,-Z8,-Z1,-Z2,-Z5, trZ} for FMA-friendly x = trZ - tr(Z R)
__device__ __forceinline__ void compute_Z_neg(const float* __restrict__ L, float zo[7]) {
    float a = L[0], l10 = L[3], c = L[4], d = L[6], e = L[7], f = L[8];
    float ia = 1.0f / a, ic = 1.0f / c, iff = 1.0f / f;
    float m00 = ia;
    float m10 = -l10 * ia * ic;
    float m11 = ic;
    float m20 = (l10 * e - c * d) * ia * ic * iff;
    float m21 = -e * ic * iff;
    float m22 = iff;
    float Z0 = m00*m00 + m10*m10 + m20*m20;
    float Z1 = m10*m11 + m20*m21;
    float Z2 = m20*m22;
    float Z4 = m11*m11 + m21*m21;
    float Z5 = m21*m22;
    float Z8 = m22*m22;
    zo[0] = -Z0; zo[1] = -Z4; zo[2] = -Z8;
    zo[3] = -Z1; zo[4] = -Z2; zo[5] = -Z5;
    zo[6] = Z0 + Z4 + Z8;
}

__device__ __forceinline__ void quat_to_mat(const float q[4], float R[9]) {
    float n = sqrtf(q[0]*q[0] + q[1]*q[1] + q[2]*q[2] + q[3]*q[3]);
    float w = q[0]/n, x = q[1]/n, y = q[2]/n, z = q[3]/n;
    R[0] = 1.f - 2.f*(y*y + z*z);
    R[1] = 2.f*(x*y - w*z);
    R[2] = 2.f*(x*z + w*y);
    R[3] = 2.f*(x*y + w*z);
    R[4] = 1.f - 2.f*(x*x + z*z);
    R[5] = 2.f*(y*z - w*x);
    R[6] = 2.f*(x*z - w*y);
    R[7] = 2.f*(y*z + w*x);
    R[8] = 1.f - 2.f*(x*x + y*y);
}

// K1: grid (NTILES, BGRPS) = 1536 blocks. async-LDS staged coalesced loads,
// 8-b register inner loop. Two-node graph (cross-block sync proven bad: R5/R7/R8).
__global__ __launch_bounds__(TPB) void k_part(
    const float* __restrict__ cov_tril,
    const float* __restrict__ grids,
    double* __restrict__ part, int B)
{
    const int tile = blockIdx.x;
    const int bg   = blockIdx.y;
    const int tid  = threadIdx.x;
    const int wave = tid >> 6;
    const int lane = tid & 63;

    __shared__ float zsh[BPB][8];
    __shared__ float gsh[CHUNK * 9];   // 9216 B raw rotation chunk
    __shared__ float red[TPB * 9];     // reduction scratch

    if (tid < BPB) {
        float zo[7];
        compute_Z_neg(cov_tril + (bg * BPB + tid) * 9, zo);
#pragma unroll
        for (int j = 0; j < 7; ++j) zsh[tid][j] = zo[j];
    }
    __syncthreads();

    float z[BPB][7];
#pragma unroll
    for (int bl = 0; bl < BPB; ++bl)
#pragma unroll
        for (int j = 0; j < 7; ++j) z[bl][j] = zsh[bl][j];

    float acc[BPB];
#pragma unroll
    for (int bl = 0; bl < BPB; ++bl) acc[bl] = 0.f;

    const char* gbase = (const char*)grids + (size_t)tile * NCHUNK * 36;

#pragma unroll
    for (int c = 0; c < NCHUNKS; ++c) {
        // async stage chunk: 9 KiB = 9 segments x 1024B; 4 waves round-robin
        const char* csrc = gbase + (size_t)c * CHUNK * 36;
        for (int s = wave; s < 9; s += 4)
            async_copy16((char*)gsh + s * 1024, csrc + s * 1024 + lane * 16);
        __syncthreads();   // compiler drains vmcnt(0) before barrier -> chunk ready

        const float* G = gsh + tid * 9;   // stride 9: conflict-free
        float G0=G[0],G1=G[1],G2=G[2],G3=G[3],G4=G[4],G5=G[5],G6=G[6],G7=G[7],G8=G[8];
        float g0 = G0, g1 = G4, g2 = G8;
        float g3 = G1 + G3, g4 = G2 + G6, g5 = G5 + G7;

#pragma unroll
        for (int bl = 0; bl < BPB; ++bl) {
            float x = z[bl][6];
            x = fmaf(z[bl][0], g0, x);
            x = fmaf(z[bl][1], g1, x);
            x = fmaf(z[bl][2], g2, x);
            x = fmaf(z[bl][3], g3, x);
            x = fmaf(z[bl][4], g4, x);
            x = fmaf(z[bl][5], g5, x);
            x = fmaxf(x, 1e-8f);
            float r = FAST_RSQ(x);            // 1/p
            float p = x * r;                  // sqrt(x)
            float e = FAST_EXP2(-LOG2E * p);  // exp(-p)
            acc[bl] = fmaf(e, r, acc[bl]);    // += exp(-p)/p
        }
        __syncthreads();   // chunk consumed before next overwrite
    }

    // two-stage block reduce: [256 threads][8 b] -> 8 sums
#pragma unroll
    for (int bl = 0; bl < BPB; ++bl) red[tid * 9 + bl] = acc[bl];
    __syncthreads();

    const int bl = tid & 7;
    const int s  = tid >> 3;
    float p_ = 0.f;
#pragma unroll
    for (int j = 0; j < 8; ++j) p_ += red[(s * 8 + j) * 9 + bl];
    __syncthreads();
    red[tid] = p_;
    __syncthreads();

    if (tid < BPB) {
        double S = 0.0;
#pragma unroll
        for (int j = 0; j < 32; ++j) S += (double)red[j * 8 + tid];
        part[(size_t)tile * B + bg * BPB + tid] = S;
    }
}

// K2: finalize per b (1 block of 256; part reads coalesced across threads)
__global__ __launch_bounds__(TPB) void k_fin(
    const float* __restrict__ gt_quat,
    const float* __restrict__ mode_quat,
    const float* __restrict__ cov_tril,
    const double* __restrict__ part,
    float* __restrict__ out, int n_total, int B)
{
    const int b = threadIdx.x;   // B == TPB == 256

    double S = 0.0;
#pragma unroll
    for (int t = 0; t < NTILES; ++t) S += part[(size_t)t * B + b];

    float zo[7];
    compute_Z_neg(cov_tril + b * 9, zo);

    float q0[4] = {mode_quat[b*4+0], mode_quat[b*4+1], mode_quat[b*4+2], mode_quat[b*4+3]};
    float qg[4] = {gt_quat[b*4+0],   gt_quat[b*4+1],   gt_quat[b*4+2],   gt_quat[b*4+3]};
    float R0[9], Rg[9];
    quat_to_mat(q0, R0);
    quat_to_mat(qg, Rg);

    float Rr[9];
#pragma unroll
    for (int i = 0; i < 3; ++i)
#pragma unroll
        for (int j = 0; j < 3; ++j)
            Rr[i*3+j] = R0[0*3+i]*Rg[0*3+j] + R0[1*3+i]*Rg[1*3+j] + R0[2*3+i]*Rg[2*3+j];

    float x = zo[6];
    x = fmaf(zo[0], Rr[0], x);
    x = fmaf(zo[1], Rr[4], x);
    x = fmaf(zo[2], Rr[8], x);
    x = fmaf(zo[3], Rr[1] + Rr[3], x);
    x = fmaf(zo[4], Rr[2] + Rr[6], x);
    x = fmaf(zo[5], Rr[5] + Rr[7], x);

    float power = sqrtf(fmaxf(x, 1e-8f));
    float logF  = (float)(log(S) - log((double)n_total));
    out[b] = logF + power + logf(power);
}

extern "C" void kernel_launch(void* const* d_in, const int* in_sizes, int n_in,
                              void* d_out, int out_size, void* d_ws, size_t ws_size,
                              hipStream_t stream) {
    const float* gt    = (const float*)d_in[0];
    const float* mode  = (const float*)d_in[1];
    const float* cov   = (const float*)d_in[2];
    const float* grids = (const float*)d_in[3];
    float* out = (float*)d_out;

    int B       = in_sizes[0] / 4;     // 256
    int n_total = in_sizes[3] / 9;     // 36864

    double* part = (double*)d_ws;      // 48*256 doubles = 96 KB

    dim3 grid(NTILES, BGRPS);          // 1536 blocks
    k_part<<<grid, TPB, 0, stream>>>(cov, grids, part, B);
    k_fin<<<1, TPB, 0, stream>>>(gt, mode, cov, part, out, n_total, B);
}